// Round 11
// baseline (234.903 us; speedup 1.0000x reference)
//
#include <hip/hip_runtime.h>
#include <hip/hip_bf16.h>
#include <stdint.h>

#define N_PTS   8192
#define D       256
#define N_E     8192
#define BETA    0.25f
#define EPS_1   1.0000001f   // 1 + 1e-7 (rounds to 1+ulp in f32, same as jnp)

typedef unsigned long long u64;
typedef __attribute__((ext_vector_type(8))) short bf16x8;   // 8 bf16 = 4 VGPR
typedef __attribute__((ext_vector_type(8))) short short8;
typedef __attribute__((ext_vector_type(4))) float f32x4;

// ---- workspace layout (bytes) ----
// Fragment-linear bf16 arrays for 16x16x32 MFMA (R2-R4 proven layout):
// element (p,k) of an 8192x256 matrix lives at
//   blk = (p>>4)*8 + (k>>5);  l = ((k>>3)&3)*16 + (p&15);  j = k&7
//   idx = blk*512 + l*8 + j
// Each 16x32 fragment is a contiguous 1KB block in lane-major order:
// global_load_lds(uniform base + lane*16) and ds_read_b128(lane*16) are both
// perfectly linear -> zero bank conflicts (verified R3-R10: conflicts = 0).
#define WS_KEYS   0
#define WS_COUNTS (N_PTS * 8)                    // 64 KB
#define WS_LOSS   (WS_COUNTS + N_E * 4)          // +32 KB
#define WS_AHI    (1 << 20)                      // 1 MB-aligned
#define WS_ALO    (WS_AHI + N_PTS * D * 2)
#define WS_BHI    (WS_ALO + N_PTS * D * 2)
#define WS_BLO    (WS_BHI + N_E * D * 2)         // total ~17 MB

__device__ __forceinline__ short f2bf(float x) {
    __hip_bfloat16 h = __float2bfloat16(x);      // RTN-even
    return *reinterpret_cast<short*>(&h);
}
__device__ __forceinline__ float bf2f(short s) {
    __hip_bfloat16 h = *reinterpret_cast<__hip_bfloat16*>(&s);
    return __bfloat162float(h);
}

#define GLOAD16(gp, lp) __builtin_amdgcn_global_load_lds(                      \
    (const __attribute__((address_space(1))) void*)(gp),                       \
    (__attribute__((address_space(3))) void*)(lp), 16, 0, 0)

// DPP f32 min step: x = min(x, x[dpp-perm(lane)]); pure VALU, no DS pipe.
// (validated on HW in R10)
#define DPP_MIN(x, ctrl)                                                       \
    x = fminf(x, __int_as_float(__builtin_amdgcn_update_dpp(                   \
            __float_as_int(x), __float_as_int(x), (ctrl), 0xF, 0xF, true)))

// ------- init + split f32 -> bf16 hi/lo, fragment-linear layout -------------
__global__ __launch_bounds__(256) void k_prep(
    const float* __restrict__ u, const float* __restrict__ cb,
    short* __restrict__ Ahi, short* __restrict__ Alo,
    short* __restrict__ Bhi, short* __restrict__ Blo,
    u64* __restrict__ keys, float* __restrict__ counts,
    double* __restrict__ loss_sum)
{
    const int tid = blockIdx.x * 256 + threadIdx.x;   // 0 .. 262143
    if (tid < N_E)   counts[tid] = 0.f;
    if (tid < N_PTS) keys[tid] = ~0ULL;
    if (tid == 0)    *loss_sum = 0.0;

    const int blk = tid >> 6;            // = (p>>4)*8 + (k>>5)
    const int l   = tid & 63;
    const int s   = blk >> 3, c = blk & 7;
    const int p   = s * 16 + (l & 15);
    const int k   = c * 32 + (l >> 4) * 8;
    const size_t gin  = (size_t)p * D + k;
    const size_t gout = (size_t)tid * 8;

    float v[8];
    short8 h8, l8;

    *(float4*)&v[0] = *(const float4*)&u[gin];
    *(float4*)&v[4] = *(const float4*)&u[gin + 4];
    if (k == 0) v[0] = -v[0];            // Minkowski sign fold on time comp
    #pragma unroll
    for (int j = 0; j < 8; ++j) {
        h8[j] = f2bf(v[j]);
        l8[j] = f2bf(v[j] - bf2f(h8[j]));
    }
    *(short8*)&Ahi[gout] = h8;
    *(short8*)&Alo[gout] = l8;

    *(float4*)&v[0] = *(const float4*)&cb[gin];
    *(float4*)&v[4] = *(const float4*)&cb[gin + 4];
    #pragma unroll
    for (int j = 0; j < 8; ++j) {
        h8[j] = f2bf(v[j]);
        l8[j] = f2bf(v[j] - bf2f(h8[j]));
    }
    *(short8*)&Bhi[gout] = h8;
    *(short8*)&Blo[gout] = l8;
}

// ---------------- MFMA argmin: C = A~ . B^T, per-row argmin, no C write ------
// split-bf16: a.b = ahi.bhi + ahi.blo + alo.bhi  (err ~2^-18 rel, safe margin)
// R4 skeleton EXACTLY (the measured optimum across R2-R10): 128x128 tile,
// 4 waves 2x2, 16x16x32 MFMA, 32 KB single-buffer LDS, 2 barriers/K-step,
// launch_bounds(256,4) -> 64 VGPR + 64 AGPR = 128/wave -> 4 waves/SIMD;
// 3-4 co-resident blocks at decorrelated phases hide each other's drains
// (empirical law R2-R10: MfmaUtil ~= Occupancy; occupancy is the lever).
// NEW vs R4: DPP epilogue (R10-validated) -- zero DS-pipe shuffles at the
// block tail -- and setprio around the MFMA clusters.
#define BMM 128
#define BNN 128
#define NKS (D / 32)         // 8 K-steps of 32

__global__ __launch_bounds__(256, 4) void k_argmin_mfma(
    const short* __restrict__ Ahi, const short* __restrict__ Alo,
    const short* __restrict__ Bhi, const short* __restrict__ Blo,
    u64* __restrict__ keys)
{
    __shared__ short sm[4][8 * 512];     // Ahi,Alo,Bhi,Blo: 8 KB each = 32 KB

    const int t   = threadIdx.x;
    const int w   = t >> 6;              // wave 0..3
    const int l   = t & 63;
    // natural order (R4-verified locality: FETCH 37 MB, L2-resident panels)
    const int rb  = blockIdx.x >> 6;     // 64 row-blocks (points)
    const int cbk = blockIdx.x & 63;     // 64 col-blocks (codes)
    const int r0  = rb * BMM, c0 = cbk * BNN;
    const int wr  = w >> 1, wc = w & 1;  // 2x2 wave grid, 64x64 each

    // staging: wave w owns one array; 8 fragment-blocks of 1KB per K-step
    const short* gsrc = (w == 0) ? Ahi : (w == 1) ? Alo : (w == 2) ? Bhi : Blo;
    short* ldst = sm[w];
    const int s0 = ((w < 2) ? rb : cbk) * 8;   // first 16-row slice index

    f32x4 acc[4][4];
    #pragma unroll
    for (int i = 0; i < 4; ++i)
        #pragma unroll
        for (int j = 0; j < 4; ++j) acc[i][j] = (f32x4){0.f, 0.f, 0.f, 0.f};

    for (int kk = 0; kk < NKS; ++kk) {
        __syncthreads();                 // prev compute done before overwrite
        #pragma unroll
        for (int i = 0; i < 8; ++i)
            GLOAD16(gsrc + (size_t)((s0 + i) * 8 + kk) * 512 + l * 8,
                    ldst + i * 512);
        __syncthreads();                 // drains vmcnt: tiles ready

        bf16x8 ah[4], al[4], bh[4], bl[4];
        #pragma unroll
        for (int f = 0; f < 4; ++f) {
            ah[f] = *(const bf16x8*)&sm[0][(wr * 4 + f) * 512 + l * 8];
            al[f] = *(const bf16x8*)&sm[1][(wr * 4 + f) * 512 + l * 8];
            bh[f] = *(const bf16x8*)&sm[2][(wc * 4 + f) * 512 + l * 8];
            bl[f] = *(const bf16x8*)&sm[3][(wc * 4 + f) * 512 + l * 8];
        }
        __builtin_amdgcn_s_setprio(1);
        #pragma unroll
        for (int mf = 0; mf < 4; ++mf)
            #pragma unroll
            for (int nf = 0; nf < 4; ++nf) {
                acc[mf][nf] = __builtin_amdgcn_mfma_f32_16x16x32_bf16(
                    ah[mf], bh[nf], acc[mf][nf], 0, 0, 0);
                acc[mf][nf] = __builtin_amdgcn_mfma_f32_16x16x32_bf16(
                    ah[mf], bl[nf], acc[mf][nf], 0, 0, 0);
                acc[mf][nf] = __builtin_amdgcn_mfma_f32_16x16x32_bf16(
                    al[mf], bh[nf], acc[mf][nf], 0, 0, 0);
            }
        __builtin_amdgcn_s_setprio(0);
    }

    // ---- DPP epilogue: per-row argmin, ZERO DS-pipe ops ----
    // C/D layout (m89-verified): col = lane&15, row = (lane>>4)*4 + reg.
    // In-lane min across nf (strict < keeps lowest code = np.argmin), then
    // f32 value-min across the 16 col-lanes via DPP mirrors (xor1/2/7/15
    // closure over the 16-group); every lane holding the row-min fires the
    // u64 atomicMin -- (value,code) key order resolves ties exactly.
    const int g  = l >> 4;
    const int cc = l & 15;
    #pragma unroll
    for (int mf = 0; mf < 4; ++mf) {
        #pragma unroll
        for (int r = 0; r < 4; ++r) {
            float mm = fmaxf(-acc[mf][0][r], EPS_1);
            unsigned code = (unsigned)(c0 + wc * 64 + cc);
            #pragma unroll
            for (int nf = 1; nf < 4; ++nf) {
                float mv = fmaxf(-acc[mf][nf][r], EPS_1);
                if (mv < mm) { mm = mv; code = (unsigned)(c0 + wc * 64 + nf * 16 + cc); }
            }
            float mv = mm;
            DPP_MIN(mv, 0xB1);           // quad_perm xor1
            DPP_MIN(mv, 0x4E);           // quad_perm xor2
            DPP_MIN(mv, 0x141);          // row_half_mirror (8-group reversal)
            DPP_MIN(mv, 0x140);          // row_mirror (16-group reversal)
            if (mm == mv) {
                const int row = r0 + wr * 64 + mf * 16 + g * 4 + r;
                u64 key = ((u64)__float_as_uint(mm) << 32) | code;
                atomicMin(&keys[row], key);
            }
        }
    }
}

// ---------------- gather z_q, per-pair f32 distance, histogram ----------------
__global__ __launch_bounds__(256) void k_gather(
    const float* __restrict__ u, const float* __restrict__ cb,
    const u64* __restrict__ keys, float* __restrict__ out,
    float* __restrict__ counts, double* __restrict__ loss_sum)
{
    __shared__ float sred[4];
    const int t    = threadIdx.x;
    const int w    = t >> 6;
    const int row  = blockIdx.x * 4 + w;
    const int lane = t & 63;
    const u64 key  = keys[row];
    const int idx  = (int)(unsigned)(key & 0xffffffffULL);

    float* zq = out + 1;
    float4 uv = *(const float4*)&u[(size_t)row * D + lane * 4];
    float4 cv = *(const float4*)&cb[(size_t)idx * D + lane * 4];
    if (lane == 0) uv.x = -uv.x;                  // Lorentzian sign
    float partial = uv.x * cv.x + uv.y * cv.y + uv.z * cv.z + uv.w * cv.w;
    *(float4*)&zq[(size_t)row * D + lane * 4] = cv;

    #pragma unroll
    for (int s = 32; s >= 1; s >>= 1)
        partial += __shfl_xor(partial, s);

    if (lane == 0) {
        float m = fmaxf(-partial, EPS_1);
        sred[w] = acoshf(m);
        atomicAdd(&counts[idx], 1.f);             // scattered: low contention
    }
    __syncthreads();
    if (t == 0)                                   // 1 f64 atomic per block
        atomicAdd(loss_sum, (double)(sred[0] + sred[1] + sred[2] + sred[3]));
}

// ---------------- scalars: loss, perplexity, entropy, e_mean -----------------
__global__ __launch_bounds__(256) void k_final(
    const float* __restrict__ counts, const double* __restrict__ loss_sum,
    float* __restrict__ out)
{
    __shared__ float red[256];
    const int t = threadIdx.x;
    const int OFF_P = 1 + N_PTS * D;
    float ent = 0.f;
    for (int i = t; i < N_E; i += 256) {
        float e = counts[i] * (1.0f / N_PTS);
        out[OFF_P + 2 + i] = e;
        ent -= e * logf(e + 1e-10f);
    }
    red[t] = ent;
    __syncthreads();
    for (int s = 128; s > 0; s >>= 1) {
        if (t < s) red[t] += red[t + s];
        __syncthreads();
    }
    if (t == 0) {
        float entropy = red[0];
        out[0]         = (1.0f + BETA) * (float)(*loss_sum / (double)N_PTS);
        out[OFF_P]     = expf(entropy);
        out[OFF_P + 1] = entropy;
    }
}

// ---------------- launch ----------------
extern "C" void kernel_launch(void* const* d_in, const int* in_sizes, int n_in,
                              void* d_out, int out_size, void* d_ws, size_t ws_size,
                              hipStream_t stream)
{
    const float* u  = (const float*)d_in[0];
    const float* cb = (const float*)d_in[1];
    float* out = (float*)d_out;
    char* ws = (char*)d_ws;

    u64*    keys     = (u64*)(ws + WS_KEYS);
    float*  counts   = (float*)(ws + WS_COUNTS);
    double* loss_sum = (double*)(ws + WS_LOSS);
    short*  Ahi = (short*)(ws + WS_AHI);
    short*  Alo = (short*)(ws + WS_ALO);
    short*  Bhi = (short*)(ws + WS_BHI);
    short*  Blo = (short*)(ws + WS_BLO);

    k_prep<<<N_PTS * D / 8 / 256, 256, 0, stream>>>(u, cb, Ahi, Alo, Bhi, Blo,
                                                    keys, counts, loss_sum);
    k_argmin_mfma<<<(N_PTS / BMM) * (N_E / BNN), 256, 0, stream>>>(
        Ahi, Alo, Bhi, Blo, keys);
    k_gather<<<N_PTS / 4, 256, 0, stream>>>(u, cb, keys, out, counts, loss_sum);
    k_final<<<1, 256, 0, stream>>>(counts, loss_sum, out);
}

// Round 12
// 151.593 us; speedup vs baseline: 1.5496x; 1.5496x over previous
//
#include <hip/hip_runtime.h>
#include <hip/hip_bf16.h>
#include <stdint.h>

#define N_PTS   8192
#define D       256
#define N_E     8192
#define BETA    0.25f
#define EPS_1   1.0000001f   // 1 + 1e-7 (rounds to 1+ulp in f32, same as jnp)

typedef unsigned long long u64;
typedef __attribute__((ext_vector_type(8))) short bf16x8;   // 8 bf16 = 4 VGPR
typedef __attribute__((ext_vector_type(8))) short short8;
typedef __attribute__((ext_vector_type(4))) float f32x4;

// ---- workspace layout (bytes) ----
// Fragment-linear bf16 arrays for 16x16x32 MFMA (R2-R4 proven layout):
// element (p,k) of an 8192x256 matrix lives at
//   blk = (p>>4)*8 + (k>>5);  l = ((k>>3)&3)*16 + (p&15);  j = k&7
//   idx = blk*512 + l*8 + j
// Each 16x32 fragment is a contiguous 1KB block in lane-major order:
// global_load_lds(uniform base + lane*16) and ds_read_b128(lane*16) are both
// perfectly linear -> zero bank conflicts (verified R3-R11: conflicts = 0).
#define WS_KEYS   0
#define WS_COUNTS (N_PTS * 8)                    // 64 KB
#define WS_LOSS   (WS_COUNTS + N_E * 4)          // +32 KB
#define WS_AHI    (1 << 20)                      // 1 MB-aligned
#define WS_ALO    (WS_AHI + N_PTS * D * 2)
#define WS_BHI    (WS_ALO + N_PTS * D * 2)
#define WS_BLO    (WS_BHI + N_E * D * 2)         // total ~17 MB

__device__ __forceinline__ short f2bf(float x) {
    __hip_bfloat16 h = __float2bfloat16(x);      // RTN-even
    return *reinterpret_cast<short*>(&h);
}
__device__ __forceinline__ float bf2f(short s) {
    __hip_bfloat16 h = *reinterpret_cast<__hip_bfloat16*>(&s);
    return __bfloat162float(h);
}

#define GLOAD16(gp, lp) __builtin_amdgcn_global_load_lds(                      \
    (const __attribute__((address_space(1))) void*)(gp),                       \
    (__attribute__((address_space(3))) void*)(lp), 16, 0, 0)

// DPP f32 min step: x = min(x, x[dpp-perm(lane)]); pure VALU, no DS pipe.
// (validated on HW in R10)
#define DPP_MIN(x, ctrl)                                                       \
    x = fminf(x, __int_as_float(__builtin_amdgcn_update_dpp(                   \
            __float_as_int(x), __float_as_int(x), (ctrl), 0xF, 0xF, true)))

// ------- init + split f32 -> bf16 hi/lo, fragment-linear layout -------------
__global__ __launch_bounds__(256) void k_prep(
    const float* __restrict__ u, const float* __restrict__ cb,
    short* __restrict__ Ahi, short* __restrict__ Alo,
    short* __restrict__ Bhi, short* __restrict__ Blo,
    u64* __restrict__ keys, float* __restrict__ counts,
    double* __restrict__ loss_sum)
{
    const int tid = blockIdx.x * 256 + threadIdx.x;   // 0 .. 262143
    if (tid < N_E)   counts[tid] = 0.f;
    if (tid < N_PTS) keys[tid] = ~0ULL;
    if (tid == 0)    *loss_sum = 0.0;

    const int blk = tid >> 6;            // = (p>>4)*8 + (k>>5)
    const int l   = tid & 63;
    const int s   = blk >> 3, c = blk & 7;
    const int p   = s * 16 + (l & 15);
    const int k   = c * 32 + (l >> 4) * 8;
    const size_t gin  = (size_t)p * D + k;
    const size_t gout = (size_t)tid * 8;

    float v[8];
    short8 h8, l8;

    *(float4*)&v[0] = *(const float4*)&u[gin];
    *(float4*)&v[4] = *(const float4*)&u[gin + 4];
    if (k == 0) v[0] = -v[0];            // Minkowski sign fold on time comp
    #pragma unroll
    for (int j = 0; j < 8; ++j) {
        h8[j] = f2bf(v[j]);
        l8[j] = f2bf(v[j] - bf2f(h8[j]));
    }
    *(short8*)&Ahi[gout] = h8;
    *(short8*)&Alo[gout] = l8;

    *(float4*)&v[0] = *(const float4*)&cb[gin];
    *(float4*)&v[4] = *(const float4*)&cb[gin + 4];
    #pragma unroll
    for (int j = 0; j < 8; ++j) {
        h8[j] = f2bf(v[j]);
        l8[j] = f2bf(v[j] - bf2f(h8[j]));
    }
    *(short8*)&Bhi[gout] = h8;
    *(short8*)&Blo[gout] = l8;
}

// ---------------- MFMA argmin: C = A~ . B^T, per-row argmin, no C write ------
// split-bf16: a.b = ahi.bhi + ahi.blo + alo.bhi  (err ~2^-18 rel, safe margin)
// EXACT R4 loop (measured optimum: 118 us, FETCH 37 MB, MfmaUtil 38%):
// 128x128 tile, 4 waves 2x2, 16x16x32 MFMA, 32 KB single-buffer LDS,
// 2 barriers/K-step, launch_bounds(256,4), natural block order.
// R12 single-variable change vs R11: setprio REMOVED (suspected L2-thrash
// trigger: R11 = R4-loop + setprio + DPP-epi showed FETCH 37->210 MB with
// identical per-dispatch work; MfmaUtil/VALUBusy scaled exactly with dur).
// DPP epilogue kept (R10-validated, zero DS-pipe ops at block tail).
#define BMM 128
#define BNN 128
#define NKS (D / 32)         // 8 K-steps of 32

__global__ __launch_bounds__(256, 4) void k_argmin_mfma(
    const short* __restrict__ Ahi, const short* __restrict__ Alo,
    const short* __restrict__ Bhi, const short* __restrict__ Blo,
    u64* __restrict__ keys)
{
    __shared__ short sm[4][8 * 512];     // Ahi,Alo,Bhi,Blo: 8 KB each = 32 KB

    const int t   = threadIdx.x;
    const int w   = t >> 6;              // wave 0..3
    const int l   = t & 63;
    // natural order (R4-verified locality: FETCH 37 MB, L2-resident panels)
    const int rb  = blockIdx.x >> 6;     // 64 row-blocks (points)
    const int cbk = blockIdx.x & 63;     // 64 col-blocks (codes)
    const int r0  = rb * BMM, c0 = cbk * BNN;
    const int wr  = w >> 1, wc = w & 1;  // 2x2 wave grid, 64x64 each

    // staging: wave w owns one array; 8 fragment-blocks of 1KB per K-step
    const short* gsrc = (w == 0) ? Ahi : (w == 1) ? Alo : (w == 2) ? Bhi : Blo;
    short* ldst = sm[w];
    const int s0 = ((w < 2) ? rb : cbk) * 8;   // first 16-row slice index

    f32x4 acc[4][4];
    #pragma unroll
    for (int i = 0; i < 4; ++i)
        #pragma unroll
        for (int j = 0; j < 4; ++j) acc[i][j] = (f32x4){0.f, 0.f, 0.f, 0.f};

    for (int kk = 0; kk < NKS; ++kk) {
        __syncthreads();                 // prev compute done before overwrite
        #pragma unroll
        for (int i = 0; i < 8; ++i)
            GLOAD16(gsrc + (size_t)((s0 + i) * 8 + kk) * 512 + l * 8,
                    ldst + i * 512);
        __syncthreads();                 // drains vmcnt: tiles ready

        bf16x8 ah[4], al[4], bh[4], bl[4];
        #pragma unroll
        for (int f = 0; f < 4; ++f) {
            ah[f] = *(const bf16x8*)&sm[0][(wr * 4 + f) * 512 + l * 8];
            al[f] = *(const bf16x8*)&sm[1][(wr * 4 + f) * 512 + l * 8];
            bh[f] = *(const bf16x8*)&sm[2][(wc * 4 + f) * 512 + l * 8];
            bl[f] = *(const bf16x8*)&sm[3][(wc * 4 + f) * 512 + l * 8];
        }
        #pragma unroll
        for (int mf = 0; mf < 4; ++mf)
            #pragma unroll
            for (int nf = 0; nf < 4; ++nf) {
                acc[mf][nf] = __builtin_amdgcn_mfma_f32_16x16x32_bf16(
                    ah[mf], bh[nf], acc[mf][nf], 0, 0, 0);
                acc[mf][nf] = __builtin_amdgcn_mfma_f32_16x16x32_bf16(
                    ah[mf], bl[nf], acc[mf][nf], 0, 0, 0);
                acc[mf][nf] = __builtin_amdgcn_mfma_f32_16x16x32_bf16(
                    al[mf], bh[nf], acc[mf][nf], 0, 0, 0);
            }
    }

    // ---- DPP epilogue: per-row argmin, ZERO DS-pipe ops ----
    // C/D layout (m89-verified): col = lane&15, row = (lane>>4)*4 + reg.
    // In-lane min across nf (strict < keeps lowest code = np.argmin), then
    // f32 value-min across the 16 col-lanes via DPP (xor1/xor2 quad closure,
    // then 8- and 16-group mirrors); every lane holding the row-min fires
    // the u64 atomicMin -- (value,code) key order resolves ties exactly.
    const int g  = l >> 4;
    const int cc = l & 15;
    #pragma unroll
    for (int mf = 0; mf < 4; ++mf) {
        #pragma unroll
        for (int r = 0; r < 4; ++r) {
            float mm = fmaxf(-acc[mf][0][r], EPS_1);
            unsigned code = (unsigned)(c0 + wc * 64 + cc);
            #pragma unroll
            for (int nf = 1; nf < 4; ++nf) {
                float mv = fmaxf(-acc[mf][nf][r], EPS_1);
                if (mv < mm) { mm = mv; code = (unsigned)(c0 + wc * 64 + nf * 16 + cc); }
            }
            float mv = mm;
            DPP_MIN(mv, 0xB1);           // quad_perm xor1
            DPP_MIN(mv, 0x4E);           // quad_perm xor2
            DPP_MIN(mv, 0x141);          // row_half_mirror (8-group reversal)
            DPP_MIN(mv, 0x140);          // row_mirror (16-group reversal)
            if (mm == mv) {
                const int row = r0 + wr * 64 + mf * 16 + g * 4 + r;
                u64 key = ((u64)__float_as_uint(mm) << 32) | code;
                atomicMin(&keys[row], key);
            }
        }
    }
}

// ---------------- gather z_q, per-pair f32 distance, histogram ----------------
__global__ __launch_bounds__(256) void k_gather(
    const float* __restrict__ u, const float* __restrict__ cb,
    const u64* __restrict__ keys, float* __restrict__ out,
    float* __restrict__ counts, double* __restrict__ loss_sum)
{
    __shared__ float sred[4];
    const int t    = threadIdx.x;
    const int w    = t >> 6;
    const int row  = blockIdx.x * 4 + w;
    const int lane = t & 63;
    const u64 key  = keys[row];
    const int idx  = (int)(unsigned)(key & 0xffffffffULL);

    float* zq = out + 1;
    float4 uv = *(const float4*)&u[(size_t)row * D + lane * 4];
    float4 cv = *(const float4*)&cb[(size_t)idx * D + lane * 4];
    if (lane == 0) uv.x = -uv.x;                  // Lorentzian sign
    float partial = uv.x * cv.x + uv.y * cv.y + uv.z * cv.z + uv.w * cv.w;
    *(float4*)&zq[(size_t)row * D + lane * 4] = cv;

    #pragma unroll
    for (int s = 32; s >= 1; s >>= 1)
        partial += __shfl_xor(partial, s);

    if (lane == 0) {
        float m = fmaxf(-partial, EPS_1);
        sred[w] = acoshf(m);
        atomicAdd(&counts[idx], 1.f);             // scattered: low contention
    }
    __syncthreads();
    if (t == 0)                                   // 1 f64 atomic per block
        atomicAdd(loss_sum, (double)(sred[0] + sred[1] + sred[2] + sred[3]));
}

// ---------------- scalars: loss, perplexity, entropy, e_mean -----------------
__global__ __launch_bounds__(256) void k_final(
    const float* __restrict__ counts, const double* __restrict__ loss_sum,
    float* __restrict__ out)
{
    __shared__ float red[256];
    const int t = threadIdx.x;
    const int OFF_P = 1 + N_PTS * D;
    float ent = 0.f;
    for (int i = t; i < N_E; i += 256) {
        float e = counts[i] * (1.0f / N_PTS);
        out[OFF_P + 2 + i] = e;
        ent -= e * logf(e + 1e-10f);
    }
    red[t] = ent;
    __syncthreads();
    for (int s = 128; s > 0; s >>= 1) {
        if (t < s) red[t] += red[t + s];
        __syncthreads();
    }
    if (t == 0) {
        float entropy = red[0];
        out[0]         = (1.0f + BETA) * (float)(*loss_sum / (double)N_PTS);
        out[OFF_P]     = expf(entropy);
        out[OFF_P + 1] = entropy;
    }
}

// ---------------- launch ----------------
extern "C" void kernel_launch(void* const* d_in, const int* in_sizes, int n_in,
                              void* d_out, int out_size, void* d_ws, size_t ws_size,
                              hipStream_t stream)
{
    const float* u  = (const float*)d_in[0];
    const float* cb = (const float*)d_in[1];
    float* out = (float*)d_out;
    char* ws = (char*)d_ws;

    u64*    keys     = (u64*)(ws + WS_KEYS);
    float*  counts   = (float*)(ws + WS_COUNTS);
    double* loss_sum = (double*)(ws + WS_LOSS);
    short*  Ahi = (short*)(ws + WS_AHI);
    short*  Alo = (short*)(ws + WS_ALO);
    short*  Bhi = (short*)(ws + WS_BHI);
    short*  Blo = (short*)(ws + WS_BLO);

    k_prep<<<N_PTS * D / 8 / 256, 256, 0, stream>>>(u, cb, Ahi, Alo, Bhi, Blo,
                                                    keys, counts, loss_sum);
    k_argmin_mfma<<<(N_PTS / BMM) * (N_E / BNN), 256, 0, stream>>>(
        Ahi, Alo, Bhi, Blo, keys);
    k_gather<<<N_PTS / 4, 256, 0, stream>>>(u, cb, keys, out, counts, loss_sum);
    k_final<<<1, 256, 0, stream>>>(counts, loss_sum, out);
}